// Round 20
// baseline (15712.064 us; speedup 1.0000x reference)
//
#include <hip/hip_runtime.h>
#include <math.h>

#define B_ 32
#define T_ 512
#define D_ 1024
#define H_ 1024
#define L_ 4
#define NTICK (T_ + L_ - 1)    // 515
#define RPD 17                 // reduce row pad (floats)
#define PACK_PER_BLK 32768     // 16 cols x 2048 k floats = 128 KB per block
#define CNT_STRIDE 16          // dwords between sub-counters (64 B = own line)
#define CNT_PER_TICK (8 * CNT_STRIDE)

typedef unsigned long long u64;

// Cross-XCD state access: agent-scope relaxed atomics (sc1) hit the MALL
// coherence point directly. No fences anywhere -> XCD L2s never invalidated.
__device__ __forceinline__ float4 load_state4(const float* p) {
    u64 a = __hip_atomic_load((const u64*)p,       __ATOMIC_RELAXED, __HIP_MEMORY_SCOPE_AGENT);
    u64 b = __hip_atomic_load((const u64*)(p + 2), __ATOMIC_RELAXED, __HIP_MEMORY_SCOPE_AGENT);
    float4 v;
    v.x = __uint_as_float((unsigned)(a & 0xffffffffu));
    v.y = __uint_as_float((unsigned)(a >> 32));
    v.z = __uint_as_float((unsigned)(b & 0xffffffffu));
    v.w = __uint_as_float((unsigned)(b >> 32));
    return v;
}

// Wait for all 256 blocks of tick t: sum 8 sub-counters (64B-spaced -> the
// release RMWs serialize only 32-deep per line instead of 256-deep on one).
// Relaxed polls + s_sleep throttle; timeout + always-release => no hang.
__device__ __forceinline__ void waitTick(const unsigned int* base) {
    int c = 0;
    for (;;) {
        unsigned s = 0;
#pragma unroll
        for (int i = 0; i < 8; ++i)
            s += __hip_atomic_load(base + i * CNT_STRIDE,
                                   __ATOMIC_RELAXED, __HIP_MEMORY_SCOPE_AGENT);
        if (s >= 256u) return;
        __builtin_amdgcn_s_sleep(16);
        if (++c > 20000) return;   // ~4 ms/tick cap
    }
}

// One-time weight repack (proven R18): Wpack[bid][col16][k2048].
__global__ __launch_bounds__(512) void lnn_repack(
    const float* __restrict__ W_in, const float* __restrict__ W_h,
    float* __restrict__ Wpack)
{
    const int bid   = blockIdx.x;
    const int layer = bid >> 6;
    const int jbase = (bid & 63) << 4;
    const float* Win_l = W_in + (size_t)layer * D_ * H_;
    const float* Wh_l  = W_h  + (size_t)layer * H_ * H_;
    float* dst = Wpack + (size_t)bid * PACK_PER_BLK;
#pragma unroll 1
    for (int i = 0; i < 16; ++i) {
        const int f  = (i << 9) + threadIdx.x;   // float4 index 0..8191
        const int d  = f << 2;
        const int jj = d >> 11;
        const int k  = d & 2047;                 // k..k+3 stay in one half
        const float* s = (k < 1024) ? &Win_l[(size_t)k * H_ + jbase + jj]
                                    : &Wh_l[(size_t)(k - 1024) * H_ + jbase + jj];
        float4 v;
        v.x = s[0];
        v.y = s[(size_t)H_];
        v.z = s[(size_t)2 * H_];
        v.w = s[(size_t)3 * H_];
        *(float4*)&dst[d] = v;
    }
}

// Reduce phase with LITERAL P (rule #20) — proven R19.
#define REDUCE_PHASE(P)                                                         \
    do {                                                                        \
        __syncthreads();                                                        \
        _Pragma("unroll")                                                       \
        for (int q = 0; q < 8; ++q) {                                           \
            red[tid * RPD + (q << 1)]     = acc[((P) << 3) + q].x;              \
            red[tid * RPD + (q << 1) + 1] = acc[((P) << 3) + q].y;              \
        }                                                                       \
        __syncthreads();                                                        \
        if (tid < 128) {                                                        \
            const int bo   = tid >> 4;                                          \
            const int bh   = ((P) << 3) + bo;                                   \
            const int js   = (tid & 15) >> 1;                                   \
            const int comp = tid & 1;                                           \
            float s = 0.f;                                                      \
            _Pragma("unroll")                                                   \
            for (int ks = 0; ks < 64; ++ks)                                     \
                s += red[((ks << 3) + js) * RPD + (bo << 1) + comp];            \
            const float dx   = tanhf(s + bias);                                 \
            const float hold = __hip_atomic_load(&hrow[(size_t)bh * H_ + jr],   \
                                __ATOMIC_RELAXED, __HIP_MEMORY_SCOPE_AGENT);    \
            const float hn   = hold + (dx - hold) / tv;                         \
            __hip_atomic_store(&wl[(size_t)bh * H_ + jr], hn,                   \
                               __ATOMIC_RELAXED, __HIP_MEMORY_SCOPE_AGENT);     \
        }                                                                       \
    } while (0)

// Stage one tile: issue 4 reg loads then ds_write them to slot dst.
#define STAGE_TILE(TSRC, TSTR, TKOF, TAT, DSTPTR)                               \
    do {                                                                        \
        float4 stg0, stg1, stg2, stg3;                                          \
        {                                                                       \
            const float* sp0 = &(TSRC)[(size_t)(srow)      * (TSTR) + (TKOF) + scol]; \
            const float* sp1 = &(TSRC)[(size_t)(srow + 8)  * (TSTR) + (TKOF) + scol]; \
            const float* sp2 = &(TSRC)[(size_t)(srow + 16) * (TSTR) + (TKOF) + scol]; \
            const float* sp3 = &(TSRC)[(size_t)(srow + 24) * (TSTR) + (TKOF) + scol]; \
            if (TAT) { stg0 = load_state4(sp0); stg1 = load_state4(sp1);        \
                       stg2 = load_state4(sp2); stg3 = load_state4(sp3); }      \
            else     { stg0 = *(const float4*)sp0; stg1 = *(const float4*)sp1;  \
                       stg2 = *(const float4*)sp2; stg3 = *(const float4*)sp3; }\
        }                                                                       \
        *(float4*)&(DSTPTR)[(size_t)(srow)      * 256 + scol] = stg0;           \
        *(float4*)&(DSTPTR)[(size_t)(srow + 8)  * 256 + scol] = stg1;           \
        *(float4*)&(DSTPTR)[(size_t)(srow + 16) * 256 + scol] = stg2;           \
        *(float4*)&(DSTPTR)[(size_t)(srow + 24) * 256 + scol] = stg3;           \
    } while (0)

// Persistent kernel: 256 blocks (1/CU), 512 threads = 8 j-pairs x 64 kslots.
// R20 vs R19 (attacking the measured ~13 us/tick serial tail):
//  (1) sub-counter release (8 x 64B-spaced): RMW serialization 256 -> 32 deep.
//  (2) pair staging: 2 tiles per barrier -> main-loop barriers 8 -> 4.
// HARD RULES kept: pair loop ROLLED (unroll 1; full unroll spills past the
// immovable 128-VGPR cap), stg live <= 4 float4, reduce indices literal.
template<bool PACKED>
__global__ __launch_bounds__(512, 2) void lnn_persist(
    const float* __restrict__ x,      // [B][T][D]
    const float* __restrict__ W_in,   // [L][D][H]
    const float* __restrict__ b_in,   // [L][H]
    const float* __restrict__ W_h,    // [L][H][H]
    const float* __restrict__ b_h,    // [L][H]
    const float* __restrict__ tau,    // [L][H]
    const float* __restrict__ Wpack,  // [256][PACK_PER_BLK] repacked weights
    float* __restrict__ buf0,         // [L][B][H] state, tick-parity 0
    float* __restrict__ buf1,         // [L][B][H] state, tick-parity 1
    unsigned int* __restrict__ count) // [NTICK][CNT_PER_TICK] sub-counters
{
    const int tid   = threadIdx.x;
    const int layer = blockIdx.x >> 6;
    const int jbase = (blockIdx.x & 63) << 4;
    const int jp    = tid & 7;        // j-pair: cols jbase+2jp, +1
    const int kslot = tid >> 3;       // 0..63
    const int kb    = kslot << 2;     // k offset within 256-tile (floats)

    __shared__ __align__(16) float smem[32768];   // 128 KB: [2 buf][2 slot][32][256]
    float* red = smem;                             // reduce aliases buf0 (idle then)

    const float* Wl_in = W_in + (size_t)layer * D_ * H_;
    const float* Wl_h  = W_h  + (size_t)layer * H_ * H_;
    const float* wbaseA = Wpack + (size_t)blockIdx.x * PACK_PER_BLK
                        + ((size_t)(jp << 1) << 11);
    const float* wbaseB = wbaseA + 2048;
    const int jgA = jbase + (jp << 1);

    // reduce-reader per-thread constants (role: jhat = tid & 15)
    const int   jr   = jbase + (tid & 15);
    const float bias = b_in[layer * H_ + jr] + b_h[layer * H_ + jr];
    const float tv   = tau[layer * H_ + jr];

    // staging role: row srow+8q, float4-col scol
    const int srow = tid >> 6;
    const int scol = (tid & 63) << 2;

    for (int tick = 0; tick < NTICK; ++tick) {
        if (tid == 0 && tick > 0)
            waitTick(count + (size_t)(tick - 1) * CNT_PER_TICK);
        __syncthreads();   // all threads ordered after the wait

        const int t = tick - layer;
        if (t >= 0 && t < T_) {
            const float* rb   = (tick & 1) ? buf0 : buf1;   // state at t-1
            float*       wb   = (tick & 1) ? buf1 : buf0;   // state at t
            const float* hrow = rb + (size_t)layer * B_ * H_;
            float*       wl   = wb + (size_t)layer * B_ * H_;

            const float* xsrc; size_t xstr;
            if (layer == 0) { xsrc = x + (size_t)t * D_;                  xstr = (size_t)T_ * D_; }
            else            { xsrc = rb + (size_t)(layer - 1) * B_ * H_;  xstr = H_; }
            const bool xat = (layer != 0);

            float2 acc[32];
#pragma unroll
            for (int i = 0; i < 32; ++i) acc[i] = make_float2(0.f, 0.f);

            // ---- prologue: stage tiles 0,1 into buf0 slots 0,1 ----
            STAGE_TILE(xsrc, xstr, 0,   xat, smem);            // tile 0 -> [0][0]
            STAGE_TILE(xsrc, xstr, 256, xat, smem + 8192);     // tile 1 -> [0][1]
            __syncthreads();

            // ---- 4 pairs of tiles; ONE barrier per pair ----
#pragma unroll 1
            for (int p = 0; p < 4; ++p) {
                const int    bufo = (p & 1) << 14;             // float offset of cur buf
                const int    nbo  = ((p & 1) ^ 1) << 14;       // next buf
                const float* cs0  = smem + bufo;               // cur slot 0
                const float* cs1  = smem + bufo + 8192;        // cur slot 1
                const int ta = (p << 1);                        // even tile
                const int tb = ta + 1;

                // tile ta: weights, then prefetch tile ta+2, then compute
                {
                    float4 wA, wB;
                    if constexpr (PACKED) {
                        wA = *(const float4*)&wbaseA[(ta << 8) + kb];
                        wB = *(const float4*)&wbaseB[(ta << 8) + kb];
                    } else {
                        const float* wp = ((ta < 4) ? Wl_in : Wl_h)
                                        + (size_t)(((ta & 3) << 8) + kb) * H_ + jgA;
                        wA.x = wp[0];            wB.x = wp[1];
                        wA.y = wp[(size_t)H_];   wB.y = wp[(size_t)H_ + 1];
                        wA.z = wp[2*(size_t)H_]; wB.z = wp[2*(size_t)H_ + 1];
                        wA.w = wp[3*(size_t)H_]; wB.w = wp[3*(size_t)H_ + 1];
                    }
                    if (p < 3) {
                        const int    nt   = ta + 2;
                        const float* nsrc = (nt < 4) ? xsrc : hrow;
                        const size_t nstr = (nt < 4) ? xstr : (size_t)H_;
                        const int    nkof = (nt & 3) << 8;
                        const bool   nat  = (nt >= 4) || xat;
                        STAGE_TILE(nsrc, nstr, nkof, nat, smem + nbo);
                        // compute AFTER staging issue: loads overlap the FMAs below
                    }
#pragma unroll
                    for (int b = 0; b < 32; ++b) {
                        const float4 a = *(const float4*)&cs0[(size_t)b * 256 + kb];
                        acc[b].x += a.x * wA.x + a.y * wA.y + a.z * wA.z + a.w * wA.w;
                        acc[b].y += a.x * wB.x + a.y * wB.y + a.z * wB.z + a.w * wB.w;
                    }
                }

                // tile tb: weights, prefetch tile tb+2, compute
                {
                    float4 wA, wB;
                    if constexpr (PACKED) {
                        wA = *(const float4*)&wbaseA[(tb << 8) + kb];
                        wB = *(const float4*)&wbaseB[(tb << 8) + kb];
                    } else {
                        const float* wp = ((tb < 4) ? Wl_in : Wl_h)
                                        + (size_t)(((tb & 3) << 8) + kb) * H_ + jgA;
                        wA.x = wp[0];            wB.x = wp[1];
                        wA.y = wp[(size_t)H_];   wB.y = wp[(size_t)H_ + 1];
                        wA.z = wp[2*(size_t)H_]; wB.z = wp[2*(size_t)H_ + 1];
                        wA.w = wp[3*(size_t)H_]; wB.w = wp[3*(size_t)H_ + 1];
                    }
                    if (p < 3) {
                        const int    nt   = tb + 2;
                        const float* nsrc = (nt < 4) ? xsrc : hrow;
                        const size_t nstr = (nt < 4) ? xstr : (size_t)H_;
                        const int    nkof = (nt & 3) << 8;
                        const bool   nat  = (nt >= 4) || xat;
                        STAGE_TILE(nsrc, nstr, nkof, nat, smem + nbo + 8192);
                    }
#pragma unroll
                    for (int b = 0; b < 32; ++b) {
                        const float4 a = *(const float4*)&cs1[(size_t)b * 256 + kb];
                        acc[b].x += a.x * wA.x + a.y * wA.y + a.z * wA.z + a.w * wA.w;
                        acc[b].y += a.x * wB.x + a.y * wB.y + a.z * wB.z + a.w * wB.w;
                    }
                }

                __syncthreads();   // pair boundary: next buf fully written
            }

            // ---- k-reduction: 4 phases, literal indices (rule #20) ----
            REDUCE_PHASE(0); REDUCE_PHASE(1); REDUCE_PHASE(2); REDUCE_PHASE(3);
        }

        // __syncthreads() drains every wave's vmem ops before the release-add.
        __syncthreads();
        if (tid == 0)
            __hip_atomic_fetch_add(count + (size_t)tick * CNT_PER_TICK
                                         + (blockIdx.x & 7) * CNT_STRIDE, 1u,
                                   __ATOMIC_RELEASE, __HIP_MEMORY_SCOPE_AGENT);
    }
}

// out[b][o] = sum_k h3[b][k] * W_out[k][o] + b_out[o]   (validated rounds 0-19)
__global__ __launch_bounds__(256) void lnn_out(
    const float* __restrict__ H3,     // [B][H]
    const float* __restrict__ W_out,  // [H][O]
    const float* __restrict__ b_out,  // [O]
    float* __restrict__ out)          // [B][O]
{
    const int gid = blockIdx.x * 256 + threadIdx.x;  // 64 blocks -> 16384 threads
    const int jj  = gid & 1023;
    const int b2  = gid >> 10;                       // 0..15 -> rows b2, b2+16
    float acc0 = b_out[jj];
    float acc1 = b_out[jj];
    for (int k = 0; k < H_; ++k) {
        const float w = W_out[k * H_ + jj];
        acc0 += H3[b2 * H_ + k]        * w;
        acc1 += H3[(b2 + 16) * H_ + k] * w;
    }
    out[b2 * H_ + jj]        = acc0;
    out[(b2 + 16) * H_ + jj] = acc1;
}

extern "C" void kernel_launch(void* const* d_in, const int* in_sizes, int n_in,
                              void* d_out, int out_size, void* d_ws, size_t ws_size,
                              hipStream_t stream) {
    const float* x     = (const float*)d_in[0];
    const float* W_in  = (const float*)d_in[1];
    const float* b_in  = (const float*)d_in[2];
    const float* W_h   = (const float*)d_in[3];
    const float* b_h   = (const float*)d_in[4];
    const float* tau   = (const float*)d_in[5];
    const float* W_out = (const float*)d_in[6];
    const float* b_out = (const float*)d_in[7];

    const size_t stateElems = (size_t)L_ * B_ * H_;          // 131072 floats
    const size_t packElems  = (size_t)256 * PACK_PER_BLK;    // 32 MB
    const size_t cntDwords  = (size_t)NTICK * CNT_PER_TICK;  // ~264 KB
    const size_t needPacked = (packElems + 2 * stateElems) * sizeof(float)
                            + cntDwords * sizeof(unsigned int);
    const bool packed = (ws_size >= needPacked);

    float* Wpack = (float*)d_ws;
    float* buf0  = packed ? (Wpack + packElems) : (float*)d_ws;
    float* buf1  = buf0 + stateElems;
    unsigned int* count = (unsigned int*)(buf1 + stateElems);

    // zero state + sub-counters (captured in graph -> reset every replay)
    (void)hipMemsetAsync(buf0, 0,
                         2 * stateElems * sizeof(float) + cntDwords * sizeof(unsigned int),
                         stream);

    if (packed) {
        lnn_repack<<<256, 512, 0, stream>>>(W_in, W_h, Wpack);
        lnn_persist<true><<<256, 512, 0, stream>>>(x, W_in, b_in, W_h, b_h, tau,
                                                   Wpack, buf0, buf1, count);
    } else {
        lnn_persist<false><<<256, 512, 0, stream>>>(x, W_in, b_in, W_h, b_h, tau,
                                                    Wpack, buf0, buf1, count);
    }

    // h3 at t=511 computed at tick 514 -> write parity 514&1 = 0 -> buf0.
    // Kernel boundary provides coherence for these plain loads.
    const float* H3 = buf0 + 3 * (B_ * H_);
    lnn_out<<<64, 256, 0, stream>>>(H3, W_out, b_out, (float*)d_out);
}

// Round 21
// 13318.021 us; speedup vs baseline: 1.1798x; 1.1798x over previous
//
#include <hip/hip_runtime.h>
#include <math.h>

#define B_ 32
#define T_ 512
#define D_ 1024
#define H_ 1024
#define L_ 4
#define RPD 17                 // reduce row pad (floats)
#define PACK_PER_BLK 32768     // 16 cols x 2048 k floats = 128 KB per block

typedef unsigned long long u64;

// Cross-XCD state access: agent-scope relaxed atomics (sc1) hit the MALL
// coherence point directly. No fences anywhere -> XCD L2s never invalidated.
__device__ __forceinline__ float4 load_state4(const float* p) {
    u64 a = __hip_atomic_load((const u64*)p,       __ATOMIC_RELAXED, __HIP_MEMORY_SCOPE_AGENT);
    u64 b = __hip_atomic_load((const u64*)(p + 2), __ATOMIC_RELAXED, __HIP_MEMORY_SCOPE_AGENT);
    float4 v;
    v.x = __uint_as_float((unsigned)(a & 0xffffffffu));
    v.y = __uint_as_float((unsigned)(a >> 32));
    v.z = __uint_as_float((unsigned)(b & 0xffffffffu));
    v.w = __uint_as_float((unsigned)(b >> 32));
    return v;
}

// Relaxed spin + s_sleep throttle; short timeout + always-release => no hang.
__device__ __forceinline__ void waitCount(const unsigned int* p, unsigned int target) {
    int c = 0;
    while (__hip_atomic_load(p, __ATOMIC_RELAXED, __HIP_MEMORY_SCOPE_AGENT) < target) {
        __builtin_amdgcn_s_sleep(16);
        if (++c > 20000) return;   // ~4 ms cap per dependency
    }
}

// One-time weight repack (proven R18): Wpack[bid][col16][k2048].
__global__ __launch_bounds__(512) void lnn_repack(
    const float* __restrict__ W_in, const float* __restrict__ W_h,
    float* __restrict__ Wpack)
{
    const int bid   = blockIdx.x;
    const int layer = bid >> 6;
    const int jbase = (bid & 63) << 4;
    const float* Win_l = W_in + (size_t)layer * D_ * H_;
    const float* Wh_l  = W_h  + (size_t)layer * H_ * H_;
    float* dst = Wpack + (size_t)bid * PACK_PER_BLK;
#pragma unroll 1
    for (int i = 0; i < 16; ++i) {
        const int f  = (i << 9) + threadIdx.x;   // float4 index 0..8191
        const int d  = f << 2;
        const int jj = d >> 11;
        const int k  = d & 2047;                 // k..k+3 stay in one half
        const float* s = (k < 1024) ? &Win_l[(size_t)k * H_ + jbase + jj]
                                    : &Wh_l[(size_t)(k - 1024) * H_ + jbase + jj];
        float4 v;
        v.x = s[0];
        v.y = s[(size_t)H_];
        v.z = s[(size_t)2 * H_];
        v.w = s[(size_t)3 * H_];
        *(float4*)&dst[d] = v;
    }
}

// Reduce phase with LITERAL P (rule #20) — proven R19.
#define REDUCE_PHASE(P)                                                         \
    do {                                                                        \
        __syncthreads();                                                        \
        _Pragma("unroll")                                                       \
        for (int q = 0; q < 8; ++q) {                                           \
            red[tid * RPD + (q << 1)]     = acc[((P) << 3) + q].x;              \
            red[tid * RPD + (q << 1) + 1] = acc[((P) << 3) + q].y;              \
        }                                                                       \
        __syncthreads();                                                        \
        if (tid < 128) {                                                        \
            const int bo   = tid >> 4;                                          \
            const int bh   = ((P) << 3) + bo;                                   \
            const int js   = (tid & 15) >> 1;                                   \
            const int comp = tid & 1;                                           \
            float s = 0.f;                                                      \
            _Pragma("unroll")                                                   \
            for (int ks = 0; ks < 64; ++ks)                                     \
                s += red[((ks << 3) + js) * RPD + (bo << 1) + comp];            \
            const float dx   = tanhf(s + bias);                                 \
            const float hold = __hip_atomic_load(&hrow[(size_t)bh * H_ + jr],   \
                                __ATOMIC_RELAXED, __HIP_MEMORY_SCOPE_AGENT);    \
            const float hn   = hold + (dx - hold) / tv;                         \
            __hip_atomic_store(&wl[(size_t)bh * H_ + jr], hn,                   \
                               __ATOMIC_RELAXED, __HIP_MEMORY_SCOPE_AGENT);     \
        }                                                                       \
    } while (0)

// Persistent kernel: 256 blocks (1/CU), 512 threads = 8 j-pairs x 64 kslots.
// R21 single variable vs R19: GLOBAL lockstep -> POINT-TO-POINT layer sync.
// Layer l at its own timestep t waits only on:
//   done[l-1][t]   (RAW: input h_{l-1}(t), fresh from the layer below)
//   done[l][t-1]   (RAW: own state h_l(t-1), all 1024 cols)
//   done[l+1][t-2] (WAR: parity buffer slot being overwritten was consumed)
// All deps sit at global-tick-1 -> acyclic; blocks advance as soon as THEIR
// neighbors are done instead of all 256 blocks (R20 null result showed the
// residual ~18 us/tick is lockstep straggle, not barriers/RMW contention).
// HARD RULES kept: tile loop ROLLED (unroll 1; full unroll spills past the
// immovable 128-VGPR cap), reduce indices literal, sc1 state protocol.
template<bool PACKED>
__global__ __launch_bounds__(512, 2) void lnn_persist(
    const float* __restrict__ x,      // [B][T][D]
    const float* __restrict__ W_in,   // [L][D][H]
    const float* __restrict__ b_in,   // [L][H]
    const float* __restrict__ W_h,    // [L][H][H]
    const float* __restrict__ b_h,    // [L][H]
    const float* __restrict__ tau,    // [L][H]
    const float* __restrict__ Wpack,  // [256][PACK_PER_BLK] repacked weights
    float* __restrict__ buf0,         // [L][B][H] state, parity 0
    float* __restrict__ buf1,         // [L][B][H] state, parity 1
    unsigned int* __restrict__ done)  // [L][T_] per-(layer,timestep) counters
{
    const int tid   = threadIdx.x;
    const int layer = blockIdx.x >> 6;
    const int jbase = (blockIdx.x & 63) << 4;
    const int jp    = tid & 7;        // j-pair: cols jbase+2jp, +1
    const int kslot = tid >> 3;       // 0..63
    const int kb    = kslot << 2;     // k offset within 256-tile (floats)

    __shared__ __align__(16) float smem[16384];     // 64 KB: xs[2][32][256]
    float (*xs)[32][256] = (float(*)[32][256])smem;
    float* red = smem;                               // reduce aliases (34.8 KB)

    const float* Wl_in = W_in + (size_t)layer * D_ * H_;
    const float* Wl_h  = W_h  + (size_t)layer * H_ * H_;
    const float* wbaseA = Wpack + (size_t)blockIdx.x * PACK_PER_BLK
                        + ((size_t)(jp << 1) << 11);
    const float* wbaseB = wbaseA + 2048;
    const int jgA = jbase + (jp << 1);

    // reduce-reader per-thread constants (role: jhat = tid & 15)
    const int   jr   = jbase + (tid & 15);
    const float bias = b_in[layer * H_ + jr] + b_h[layer * H_ + jr];
    const float tv   = tau[layer * H_ + jr];

    // staging role: e = q*512 + tid -> row e>>6, float4-col e&63
    const int srow = tid >> 6;
    const int scol = (tid & 63) << 2;

    for (int t = 0; t < T_; ++t) {
        if (tid == 0) {
            if (layer > 0)             waitCount(&done[(layer - 1) * T_ + t],     64u);
            if (t >= 1)                waitCount(&done[layer * T_ + (t - 1)],     64u);
            if (layer < 3 && t >= 2)   waitCount(&done[(layer + 1) * T_ + (t - 2)], 64u);
        }
        __syncthreads();   // all threads ordered after the waits

        const int par = (t + layer) & 1;            // global-tick parity
        const float* rb   = par ? buf0 : buf1;      // state at t-1
        float*       wb   = par ? buf1 : buf0;      // state at t
        const float* hrow = rb + (size_t)layer * B_ * H_;
        float*       wl   = wb + (size_t)layer * B_ * H_;

        const float* xsrc; size_t xstr;
        if (layer == 0) { xsrc = x + (size_t)t * D_;                  xstr = (size_t)T_ * D_; }
        else            { xsrc = rb + (size_t)(layer - 1) * B_ * H_;  xstr = H_; }

        float2 acc[32];
#pragma unroll
        for (int i = 0; i < 32; ++i) acc[i] = make_float2(0.f, 0.f);

        // ---- prologue: stage tile 0 into xs[0] ----
        {
            const bool at0 = (layer != 0);
#pragma unroll
            for (int q = 0; q < 4; ++q) {
                const int r = srow + (q << 3);
                const float* sp = &xsrc[(size_t)r * xstr + scol];
                float4 v = at0 ? load_state4(sp) : *(const float4*)sp;
                *(float4*)&xs[0][r][scol] = v;
            }
        }
        __syncthreads();

#pragma unroll 1
        for (int tile = 0; tile < 8; ++tile) {
            const int cur = tile & 1;

            // (1) this tile's weights FIRST (FMAs wait only on these)
            float4 wA, wB;
            if constexpr (PACKED) {
                wA = *(const float4*)&wbaseA[(tile << 8) + kb];
                wB = *(const float4*)&wbaseB[(tile << 8) + kb];
            } else {
                const int kof = (tile & 3) << 8;
                const float* wp = ((tile < 4) ? Wl_in : Wl_h)
                                + (size_t)(kof + kb) * H_ + jgA;
                wA.x = wp[0];            wB.x = wp[1];
                wA.y = wp[(size_t)H_];   wB.y = wp[(size_t)H_ + 1];
                wA.z = wp[2*(size_t)H_]; wB.z = wp[2*(size_t)H_ + 1];
                wA.w = wp[3*(size_t)H_]; wB.w = wp[3*(size_t)H_ + 1];
            }

            // (2) issue NEXT tile's staging loads (latency hides under (3))
            float4 stg[4];
            if (tile < 7) {
                const int    nt   = tile + 1;
                const float* nsrc = (nt < 4) ? xsrc : hrow;
                const size_t nstr = (nt < 4) ? xstr : (size_t)H_;
                const int    nkof = (nt & 3) << 8;
                const bool   nat  = (nt >= 4) || (layer != 0);
#pragma unroll
                for (int q = 0; q < 4; ++q) {
                    const int r = srow + (q << 3);
                    const float* sp = &nsrc[(size_t)r * nstr + nkof + scol];
                    stg[q] = nat ? load_state4(sp) : *(const float4*)sp;
                }
            }

            // (3) compute this tile: 32 rows x {1 ds_read_b128 + 8 FMA}
#pragma unroll
            for (int b = 0; b < 32; ++b) {
                const float4 a = *(const float4*)&xs[cur][b][kb];
                acc[b].x += a.x * wA.x + a.y * wA.y + a.z * wA.z + a.w * wA.w;
                acc[b].y += a.x * wB.x + a.y * wB.y + a.z * wB.z + a.w * wB.w;
            }

            // (4) write staged regs to the other buffer; ONE barrier/tile
            if (tile < 7) {
#pragma unroll
                for (int q = 0; q < 4; ++q)
                    *(float4*)&xs[cur ^ 1][srow + (q << 3)][scol] = stg[q];
            }
            __syncthreads();
        }

        // ---- k-reduction: 4 phases, literal indices (rule #20) ----
        REDUCE_PHASE(0); REDUCE_PHASE(1); REDUCE_PHASE(2); REDUCE_PHASE(3);

        // __syncthreads() drains every wave's vmem ops (s_waitcnt vmcnt(0)
        // before s_barrier) -> all sc1 stores at MALL before the release-add.
        __syncthreads();
        if (tid == 0)
            __hip_atomic_fetch_add(&done[layer * T_ + t], 1u,
                                   __ATOMIC_RELEASE, __HIP_MEMORY_SCOPE_AGENT);
    }
}

// out[b][o] = sum_k h3[b][k] * W_out[k][o] + b_out[o]   (validated rounds 0-20)
__global__ __launch_bounds__(256) void lnn_out(
    const float* __restrict__ H3,     // [B][H]
    const float* __restrict__ W_out,  // [H][O]
    const float* __restrict__ b_out,  // [O]
    float* __restrict__ out)          // [B][O]
{
    const int gid = blockIdx.x * 256 + threadIdx.x;  // 64 blocks -> 16384 threads
    const int jj  = gid & 1023;
    const int b2  = gid >> 10;                       // 0..15 -> rows b2, b2+16
    float acc0 = b_out[jj];
    float acc1 = b_out[jj];
    for (int k = 0; k < H_; ++k) {
        const float w = W_out[k * H_ + jj];
        acc0 += H3[b2 * H_ + k]        * w;
        acc1 += H3[(b2 + 16) * H_ + k] * w;
    }
    out[b2 * H_ + jj]        = acc0;
    out[(b2 + 16) * H_ + jj] = acc1;
}

extern "C" void kernel_launch(void* const* d_in, const int* in_sizes, int n_in,
                              void* d_out, int out_size, void* d_ws, size_t ws_size,
                              hipStream_t stream) {
    const float* x     = (const float*)d_in[0];
    const float* W_in  = (const float*)d_in[1];
    const float* b_in  = (const float*)d_in[2];
    const float* W_h   = (const float*)d_in[3];
    const float* b_h   = (const float*)d_in[4];
    const float* tau   = (const float*)d_in[5];
    const float* W_out = (const float*)d_in[6];
    const float* b_out = (const float*)d_in[7];

    const size_t stateElems = (size_t)L_ * B_ * H_;          // 131072 floats
    const size_t packElems  = (size_t)256 * PACK_PER_BLK;    // 32 MB
    const size_t cntDwords  = (size_t)L_ * T_;               // 2048 counters
    const size_t needPacked = (packElems + 2 * stateElems) * sizeof(float)
                            + cntDwords * sizeof(unsigned int);
    const bool packed = (ws_size >= needPacked);

    float* Wpack = (float*)d_ws;
    float* buf0  = packed ? (Wpack + packElems) : (float*)d_ws;
    float* buf1  = buf0 + stateElems;
    unsigned int* done = (unsigned int*)(buf1 + stateElems);

    // zero state + done counters (captured in graph -> reset every replay)
    (void)hipMemsetAsync(buf0, 0,
                         2 * stateElems * sizeof(float) + cntDwords * sizeof(unsigned int),
                         stream);

    if (packed) {
        lnn_repack<<<256, 512, 0, stream>>>(W_in, W_h, Wpack);
        lnn_persist<true><<<256, 512, 0, stream>>>(x, W_in, b_in, W_h, b_h, tau,
                                                   Wpack, buf0, buf1, done);
    } else {
        lnn_persist<false><<<256, 512, 0, stream>>>(x, W_in, b_in, W_h, b_h, tau,
                                                    Wpack, buf0, buf1, done);
    }

    // h3 at t=511: parity (511+3)&1 = 0 -> written into buf0.
    // Kernel boundary provides coherence for these plain loads.
    const float* H3 = buf0 + 3 * (B_ * H_);
    lnn_out<<<64, 256, 0, stream>>>(H3, W_out, b_out, (float*)d_out);
}